// Round 9
// baseline (474.588 us; speedup 1.0000x reference)
//
#include <hip/hip_runtime.h>
#include <hip/hip_bf16.h>

#define NN 8192
#define FF 128
#define KS 8
#define KCH (NN / KS)      // 1024 K per block

typedef __attribute__((ext_vector_type(8))) short bf16x8;   // 8 bf16 (4 VGPR)
typedef __attribute__((ext_vector_type(4))) float f32x4;

__device__ __forceinline__ short f2bf(float f) {
  unsigned u = __float_as_uint(f);
  u += 0x7FFFu + ((u >> 16) & 1u);
  return (short)(u >> 16);
}
__device__ __forceinline__ float bf2f(short s) {
  return __uint_as_float(((unsigned)(unsigned short)s) << 16);
}

// ---- kernel 1: deg[i] = rowsum(adj)+1 ; dinv[i] = (deg+1e-8)^-0.5 ----
__global__ __launch_bounds__(256) void k_deg(const float* __restrict__ adj,
                                             float* __restrict__ dinv) {
  const int row = blockIdx.x;
  const float4* p = (const float4*)(adj + (size_t)row * NN);
  float s = 0.f;
#pragma unroll
  for (int it = 0; it < 8; ++it) {
    float4 v = p[it * 256 + threadIdx.x];
    s += (v.x + v.y) + (v.z + v.w);
  }
#pragma unroll
  for (int off = 32; off > 0; off >>= 1) s += __shfl_down(s, off, 64);
  __shared__ float partial[4];
  if ((threadIdx.x & 63) == 0) partial[threadIdx.x >> 6] = s;
  __syncthreads();
  if (threadIdx.x == 0) {
    float deg = (partial[0] + partial[1]) + (partial[2] + partial[3]) + 1.0f;
    dinv[row] = 1.0f / sqrtf(deg + 1e-8f);
  }
}

// ---- kernel 2: yT[f][i] = dinv[i] * x[i][f]  (bf16, transposed for NT GEMM) ----
__global__ __launch_bounds__(256) void k_scale_t(const float* __restrict__ x,
                                                 const float* __restrict__ dinv,
                                                 short* __restrict__ yT) {
  __shared__ float tile[64][129];
  const int r0 = blockIdx.x * 64;
  const int tid = threadIdx.x;
#pragma unroll
  for (int it = 0; it < 8; ++it) {
    int q = it * 256 + tid;
    int r = q >> 5;
    int c = q & 31;
    float4 v = ((const float4*)(x + (size_t)(r0 + r) * FF))[c];
    float d = dinv[r0 + r];
    tile[r][c * 4 + 0] = v.x * d;
    tile[r][c * 4 + 1] = v.y * d;
    tile[r][c * 4 + 2] = v.z * d;
    tile[r][c * 4 + 3] = v.w * d;
  }
  __syncthreads();
  const int f = tid >> 1;
  const int i0 = (tid & 1) * 32;
#pragma unroll
  for (int g = 0; g < 4; ++g) {
    bf16x8 o;
#pragma unroll
    for (int j = 0; j < 8; ++j) o[j] = f2bf(tile[i0 + g * 8 + j][f]);
    *(bf16x8*)(yT + (size_t)f * NN + r0 + i0 + g * 8) = o;
  }
}

// ---- kernel 3: zpart[ks] = adj[:, ksliced] @ y. Barrier-free MFMA GEMM. ----
// 2048 blocks (256 M-tiles x 8 K-slices), 512 thr = 8 waves, each wave an
// independent free-running 32x16 output strip (no LDS, no barriers). All 8
// waves of a block read the same A fragments (L1 absorbs); B (yT slice,
// 256 KB/slice) is L2-resident. 4-deep register K-pipeline, statically
// unrolled: ~16 loads in flight per wave continuously -> smooth VMEM issue
// like k_deg. A-frag wave-load = 16 full 128-B cache lines. f32->bf16 cvt at
// consume time. VGPR ~100 -> 16 waves/CU.
__global__ __launch_bounds__(512, 4) void k_gemm(const float* __restrict__ adj,
                                                 const short* __restrict__ yT,
                                                 short* __restrict__ zpart) {
  const int tid = threadIdx.x;
  const int wave = tid >> 6;
  const int lane = tid & 63;
  const int mb = 255 - (int)(blockIdx.x & 255);   // reverse: read L3-warm rows first
  const int ks = blockIdx.x >> 8;
  const int row0 = mb * 32;
  const int col0 = wave * 16;
  const int fr = lane & 15;
  const int kh = (lane >> 4) * 8;
  const size_t kbase = (size_t)ks * KCH;

  const float* pa0 = adj + (size_t)(row0 + fr) * NN + kbase + kh;   // rows 0..15
  const float* pa1 = pa0 + (size_t)16 * NN;                          // rows 16..31
  const short* pb  = yT + (size_t)(col0 + fr) * NN + kbase + kh;

  f32x4 acc0 = {0.f, 0.f, 0.f, 0.f};
  f32x4 acc1 = {0.f, 0.f, 0.f, 0.f};

  float4 a0lo[4], a0hi[4], a1lo[4], a1hi[4];
  bf16x8 bv[4];

#define LOADS(j, kg) do {                                                      \
    a0lo[j] = *(const float4*)(pa0 + (kg));                                    \
    a0hi[j] = *(const float4*)(pa0 + (kg) + 4);                                \
    a1lo[j] = *(const float4*)(pa1 + (kg));                                    \
    a1hi[j] = *(const float4*)(pa1 + (kg) + 4);                                \
    bv[j]   = *(const bf16x8*)(pb + (kg));                                     \
  } while (0)

#define CVT8(dst, lo, hi) do {                                                 \
    dst[0] = f2bf(lo.x); dst[1] = f2bf(lo.y);                                  \
    dst[2] = f2bf(lo.z); dst[3] = f2bf(lo.w);                                  \
    dst[4] = f2bf(hi.x); dst[5] = f2bf(hi.y);                                  \
    dst[6] = f2bf(hi.z); dst[7] = f2bf(hi.w);                                  \
  } while (0)

  LOADS(0, 0);
  LOADS(1, 32);
  LOADS(2, 64);
  LOADS(3, 96);

  for (int k0 = 0; k0 < KCH; k0 += 128) {
#pragma unroll
    for (int j = 0; j < 4; ++j) {
      bf16x8 a0, a1;
      CVT8(a0, a0lo[j], a0hi[j]);
      CVT8(a1, a1lo[j], a1hi[j]);
      bf16x8 b = bv[j];
      int kn = k0 + j * 32 + 128;
      if (kn < KCH) LOADS(j, kn);    // wave-uniform guard; issues under MFMAs
      acc0 = __builtin_amdgcn_mfma_f32_16x16x32_bf16(a0, b, acc0, 0, 0, 0);
      acc1 = __builtin_amdgcn_mfma_f32_16x16x32_bf16(a1, b, acc1, 0, 0, 0);
    }
  }
#undef LOADS
#undef CVT8

  // epilogue: D layout col=lane&15, row=(lane>>4)*4+r ; store bf16 partials
  const int r4 = (lane >> 4) * 4;
  short* zp = zpart + ((size_t)ks << 20);   // slice stride 8192*128
#pragma unroll
  for (int r = 0; r < 4; ++r) {
    int gi0 = row0 + r4 + r;
    int gi1 = gi0 + 16;
    zp[(size_t)gi0 * FF + col0 + fr] = f2bf(acc0[r]);
    zp[(size_t)gi1 * FF + col0 + fr] = f2bf(acc1[r]);
  }
}

// ---- kernel 4: out = relu((dinv*(sum_ks zpart + dinv*x)) @ W) ----
__global__ __launch_bounds__(256) void k_out(const short* __restrict__ zpart,
                                             const float* __restrict__ x,
                                             const float* __restrict__ dinv,
                                             const float* __restrict__ w,
                                             float* __restrict__ out) {
  __shared__ float zs[16][128];
  const int r0 = blockIdx.x * 16;
  const int tid = threadIdx.x;
#pragma unroll
  for (int half = 0; half < 2; ++half) {
    int p = half * 256 + tid;
    int r = p >> 5;
    int c4 = p & 31;
    int gi = r0 + r;
    const short* base = zpart + (size_t)gi * FF + c4 * 4;
    float s0 = 0.f, s1 = 0.f, s2 = 0.f, s3 = 0.f;
#pragma unroll
    for (int sidx = 0; sidx < KS; ++sidx) {
      short4 v = *(const short4*)(base + ((size_t)sidx << 20));
      s0 += bf2f(v.x); s1 += bf2f(v.y); s2 += bf2f(v.z); s3 += bf2f(v.w);
    }
    float4 xv = *(const float4*)(x + (size_t)gi * FF + c4 * 4);
    float di = dinv[gi];
    float di2 = di * di;
    zs[r][c4 * 4 + 0] = di * s0 + di2 * xv.x;
    zs[r][c4 * 4 + 1] = di * s1 + di2 * xv.y;
    zs[r][c4 * 4 + 2] = di * s2 + di2 * xv.z;
    zs[r][c4 * 4 + 3] = di * s3 + di2 * xv.w;
  }
  __syncthreads();
  const int f = tid & 127;
  const int rg = (tid >> 7) * 8;
  float acc[8] = {0.f, 0.f, 0.f, 0.f, 0.f, 0.f, 0.f, 0.f};
#pragma unroll 4
  for (int k = 0; k < 128; ++k) {
    float wv = w[k * FF + f];
#pragma unroll
    for (int r = 0; r < 8; ++r) acc[r] += zs[rg + r][k] * wv;
  }
#pragma unroll
  for (int r = 0; r < 8; ++r) {
    out[(size_t)(r0 + rg + r) * FF + f] = fmaxf(acc[r], 0.0f);
  }
}

extern "C" void kernel_launch(void* const* d_in, const int* in_sizes, int n_in,
                              void* d_out, int out_size, void* d_ws, size_t ws_size,
                              hipStream_t stream) {
  const float* x   = (const float*)d_in[0];
  const float* adj = (const float*)d_in[1];
  const float* w   = (const float*)d_in[2];
  float* out = (float*)d_out;

  float* dinv  = (float*)d_ws;                                  // 32 KiB @ 0
  short* yT    = (short*)((char*)d_ws + 64 * 1024);             // 2 MiB bf16 [128][8192]
  short* zpart = (short*)((char*)d_ws + 4 * 1024 * 1024);       // 16 MiB bf16 [8][8192][128]

  k_deg    <<<NN,       256, 0, stream>>>(adj, dinv);
  k_scale_t<<<NN / 64,  256, 0, stream>>>(x, dinv, yT);
  k_gemm   <<<256 * KS, 512, 0, stream>>>(adj, yT, zpart);
  k_out    <<<NN / 16,  256, 0, stream>>>(zpart, x, dinv, w, out);
}

// Round 10
// 344.928 us; speedup vs baseline: 1.3759x; 1.3759x over previous
//
#include <hip/hip_runtime.h>
#include <hip/hip_bf16.h>

#define NN 8192
#define FF 128
#define KS 8
#define KCH (NN / KS)      // 1024 K per block
#define NIT (KCH / 128)    // 8 outer iterations

typedef __attribute__((ext_vector_type(8))) short bf16x8;   // 8 bf16 (4 VGPR)
typedef __attribute__((ext_vector_type(4))) float f32x4;

__device__ __forceinline__ short f2bf(float f) {
  unsigned u = __float_as_uint(f);
  u += 0x7FFFu + ((u >> 16) & 1u);
  return (short)(u >> 16);
}
__device__ __forceinline__ float bf2f(short s) {
  return __uint_as_float(((unsigned)(unsigned short)s) << 16);
}

// ---- kernel 1: deg[i] = rowsum(adj)+1 ; dinv[i] = (deg+1e-8)^-0.5 ----
__global__ __launch_bounds__(256) void k_deg(const float* __restrict__ adj,
                                             float* __restrict__ dinv) {
  const int row = blockIdx.x;
  const float4* p = (const float4*)(adj + (size_t)row * NN);
  float s = 0.f;
#pragma unroll
  for (int it = 0; it < 8; ++it) {
    float4 v = p[it * 256 + threadIdx.x];
    s += (v.x + v.y) + (v.z + v.w);
  }
#pragma unroll
  for (int off = 32; off > 0; off >>= 1) s += __shfl_down(s, off, 64);
  __shared__ float partial[4];
  if ((threadIdx.x & 63) == 0) partial[threadIdx.x >> 6] = s;
  __syncthreads();
  if (threadIdx.x == 0) {
    float deg = (partial[0] + partial[1]) + (partial[2] + partial[3]) + 1.0f;
    dinv[row] = 1.0f / sqrtf(deg + 1e-8f);
  }
}

// ---- kernel 2: yT[f][i] = dinv[i] * x[i][f]  (bf16, transposed for NT GEMM) ----
__global__ __launch_bounds__(256) void k_scale_t(const float* __restrict__ x,
                                                 const float* __restrict__ dinv,
                                                 short* __restrict__ yT) {
  __shared__ float tile[64][129];
  const int r0 = blockIdx.x * 64;
  const int tid = threadIdx.x;
#pragma unroll
  for (int it = 0; it < 8; ++it) {
    int q = it * 256 + tid;
    int r = q >> 5;
    int c = q & 31;
    float4 v = ((const float4*)(x + (size_t)(r0 + r) * FF))[c];
    float d = dinv[r0 + r];
    tile[r][c * 4 + 0] = v.x * d;
    tile[r][c * 4 + 1] = v.y * d;
    tile[r][c * 4 + 2] = v.z * d;
    tile[r][c * 4 + 3] = v.w * d;
  }
  __syncthreads();
  const int f = tid >> 1;
  const int i0 = (tid & 1) * 32;
#pragma unroll
  for (int g = 0; g < 4; ++g) {
    bf16x8 o;
#pragma unroll
    for (int j = 0; j < 8; ++j) o[j] = f2bf(tile[i0 + g * 8 + j][f]);
    *(bf16x8*)(yT + (size_t)f * NN + r0 + i0 + g * 8) = o;
  }
}

// ---- kernel 3: zpart[ks] = adj[:, ksliced] @ y. Barrier-free MFMA GEMM. ----
// 2048 blocks (256 M-tiles x 8 K-slices), 512 thr = 8 waves, each wave a
// free-running 32x16 output strip: no LDS, no barriers. All 8 waves of a
// block read IDENTICAL A addresses (L1 serves 7/8); B (yT K-slice, 256 KB)
// is L2-resident. 4-deep statically-unrolled register ring (~20 loads in
// flight/wave). waves_per_eu(4,4) pins VGPR budget at 128 so the occupancy
// heuristic cannot squeeze to 64 and spill (R9's failure: VGPR=64,
// WRITE_SIZE 536 MB of scratch). Base pointers advance 512 B/iter; all load
// offsets are compile-time immediates (fold into offset:, no addr regs).
__global__ __launch_bounds__(512)
__attribute__((amdgpu_waves_per_eu(4, 4)))
void k_gemm(const float* __restrict__ adj,
            const short* __restrict__ yT,
            short* __restrict__ zpart) {
  const int tid = threadIdx.x;
  const int wave = tid >> 6;
  const int lane = tid & 63;
  const int mb = 255 - (int)(blockIdx.x & 255);   // reverse: read L3-warm rows first
  const int ks = blockIdx.x >> 8;
  const int row0 = mb * 32;
  const int col0 = wave * 16;
  const int fr = lane & 15;
  const int kh = (lane >> 4) * 8;
  const size_t kbase = (size_t)ks * KCH;

  const float* pa0 = adj + (size_t)(row0 + fr) * NN + kbase + kh;   // rows 0..15
  const float* pa1 = pa0 + (size_t)16 * NN;                          // rows 16..31
  const short* pb  = yT + (size_t)(col0 + fr) * NN + kbase + kh;

  f32x4 acc0 = {0.f, 0.f, 0.f, 0.f};
  f32x4 acc1 = {0.f, 0.f, 0.f, 0.f};

  float4 a0lo[4], a0hi[4], a1lo[4], a1hi[4];
  bf16x8 bv[4];

#define LOADS(j, kg) do {                                                      \
    a0lo[j] = *(const float4*)(pa0 + (kg));                                    \
    a0hi[j] = *(const float4*)(pa0 + (kg) + 4);                                \
    a1lo[j] = *(const float4*)(pa1 + (kg));                                    \
    a1hi[j] = *(const float4*)(pa1 + (kg) + 4);                                \
    bv[j]   = *(const bf16x8*)(pb + (kg));                                     \
  } while (0)

#define CVT8(dst, lo, hi) do {                                                 \
    dst[0] = f2bf(lo.x); dst[1] = f2bf(lo.y);                                  \
    dst[2] = f2bf(lo.z); dst[3] = f2bf(lo.w);                                  \
    dst[4] = f2bf(hi.x); dst[5] = f2bf(hi.y);                                  \
    dst[6] = f2bf(hi.z); dst[7] = f2bf(hi.w);                                  \
  } while (0)

  // prologue: 4 sets in flight (static offsets 0..384 floats)
  LOADS(0, 0);
  LOADS(1, 32);
  LOADS(2, 64);
  LOADS(3, 96);

  for (int it = 0; it < NIT; ++it) {
    const bool more = (it + 1 < NIT);   // wave-uniform
#pragma unroll
    for (int j = 0; j < 4; ++j) {
      bf16x8 a0, a1;
      CVT8(a0, a0lo[j], a0hi[j]);
      CVT8(a1, a1lo[j], a1hi[j]);
      bf16x8 b = bv[j];
      if (more) LOADS(j, 128 + j * 32);   // next iter's set j; imm offsets <=896B
      acc0 = __builtin_amdgcn_mfma_f32_16x16x32_bf16(a0, b, acc0, 0, 0, 0);
      acc1 = __builtin_amdgcn_mfma_f32_16x16x32_bf16(a1, b, acc1, 0, 0, 0);
    }
    pa0 += 128; pa1 += 128; pb += 128;    // advance bases 512 B
  }
#undef LOADS
#undef CVT8

  // epilogue: D layout col=lane&15, row=(lane>>4)*4+r ; store bf16 partials
  const int r4 = (lane >> 4) * 4;
  short* zp = zpart + ((size_t)ks << 20);   // slice stride 8192*128
#pragma unroll
  for (int r = 0; r < 4; ++r) {
    int gi0 = row0 + r4 + r;
    int gi1 = gi0 + 16;
    zp[(size_t)gi0 * FF + col0 + fr] = f2bf(acc0[r]);
    zp[(size_t)gi1 * FF + col0 + fr] = f2bf(acc1[r]);
  }
}

// ---- kernel 4: out = relu((dinv*(sum_ks zpart + dinv*x)) @ W) ----
__global__ __launch_bounds__(256) void k_out(const short* __restrict__ zpart,
                                             const float* __restrict__ x,
                                             const float* __restrict__ dinv,
                                             const float* __restrict__ w,
                                             float* __restrict__ out) {
  __shared__ float zs[16][128];
  const int r0 = blockIdx.x * 16;
  const int tid = threadIdx.x;
#pragma unroll
  for (int half = 0; half < 2; ++half) {
    int p = half * 256 + tid;
    int r = p >> 5;
    int c4 = p & 31;
    int gi = r0 + r;
    const short* base = zpart + (size_t)gi * FF + c4 * 4;
    float s0 = 0.f, s1 = 0.f, s2 = 0.f, s3 = 0.f;
#pragma unroll
    for (int sidx = 0; sidx < KS; ++sidx) {
      short4 v = *(const short4*)(base + ((size_t)sidx << 20));
      s0 += bf2f(v.x); s1 += bf2f(v.y); s2 += bf2f(v.z); s3 += bf2f(v.w);
    }
    float4 xv = *(const float4*)(x + (size_t)gi * FF + c4 * 4);
    float di = dinv[gi];
    float di2 = di * di;
    zs[r][c4 * 4 + 0] = di * s0 + di2 * xv.x;
    zs[r][c4 * 4 + 1] = di * s1 + di2 * xv.y;
    zs[r][c4 * 4 + 2] = di * s2 + di2 * xv.z;
    zs[r][c4 * 4 + 3] = di * s3 + di2 * xv.w;
  }
  __syncthreads();
  const int f = tid & 127;
  const int rg = (tid >> 7) * 8;
  float acc[8] = {0.f, 0.f, 0.f, 0.f, 0.f, 0.f, 0.f, 0.f};
#pragma unroll 4
  for (int k = 0; k < 128; ++k) {
    float wv = w[k * FF + f];
#pragma unroll
    for (int r = 0; r < 8; ++r) acc[r] += zs[rg + r][k] * wv;
  }
#pragma unroll
  for (int r = 0; r < 8; ++r) {
    out[(size_t)(r0 + rg + r) * FF + f] = fmaxf(acc[r], 0.0f);
  }
}

extern "C" void kernel_launch(void* const* d_in, const int* in_sizes, int n_in,
                              void* d_out, int out_size, void* d_ws, size_t ws_size,
                              hipStream_t stream) {
  const float* x   = (const float*)d_in[0];
  const float* adj = (const float*)d_in[1];
  const float* w   = (const float*)d_in[2];
  float* out = (float*)d_out;

  float* dinv  = (float*)d_ws;                                  // 32 KiB @ 0
  short* yT    = (short*)((char*)d_ws + 64 * 1024);             // 2 MiB bf16 [128][8192]
  short* zpart = (short*)((char*)d_ws + 4 * 1024 * 1024);       // 16 MiB bf16 [8][8192][128]

  k_deg    <<<NN,       256, 0, stream>>>(adj, dinv);
  k_scale_t<<<NN / 64,  256, 0, stream>>>(x, dinv, yT);
  k_gemm   <<<256 * KS, 512, 0, stream>>>(adj, yT, zpart);
  k_out    <<<NN / 16,  256, 0, stream>>>(zpart, x, dinv, w, out);
}

// Round 11
// 120.230 us; speedup vs baseline: 3.9473x; 2.8689x over previous
//
#include <hip/hip_runtime.h>
#include <hip/hip_bf16.h>

#define NN 8192
#define FF 128
#define BM 64
#define BK 32
#define KS 8
#define KCH (NN / KS)      // 1024 K per block
#define NSTEP (KCH / BK)   // 32

typedef __attribute__((ext_vector_type(8))) short bf16x8;   // 8 bf16 (4 VGPR)
typedef __attribute__((ext_vector_type(4))) short s16x4;
typedef __attribute__((ext_vector_type(4))) float f32x4;

__device__ __forceinline__ short f2bf(float f) {
  unsigned u = __float_as_uint(f);
  u += 0x7FFFu + ((u >> 16) & 1u);
  return (short)(u >> 16);
}
__device__ __forceinline__ float bf2f(short s) {
  return __uint_as_float(((unsigned)(unsigned short)s) << 16);
}

// raw barrier: ds-ops drained (lgkmcnt(0)) but global loads stay in flight.
#define BAR() do {                                              \
    asm volatile("s_waitcnt lgkmcnt(0)" ::: "memory");          \
    __builtin_amdgcn_s_barrier();                               \
  } while (0)

// ---- kernel 1: deg[i] = rowsum(adj)+1 ; dinv[i] = (deg+1e-8)^-0.5 ----
__global__ __launch_bounds__(256) void k_deg(const float* __restrict__ adj,
                                             float* __restrict__ dinv) {
  const int row = blockIdx.x;
  const float4* p = (const float4*)(adj + (size_t)row * NN);
  float s = 0.f;
#pragma unroll
  for (int it = 0; it < 8; ++it) {
    float4 v = p[it * 256 + threadIdx.x];
    s += (v.x + v.y) + (v.z + v.w);
  }
#pragma unroll
  for (int off = 32; off > 0; off >>= 1) s += __shfl_down(s, off, 64);
  __shared__ float partial[4];
  if ((threadIdx.x & 63) == 0) partial[threadIdx.x >> 6] = s;
  __syncthreads();
  if (threadIdx.x == 0) {
    float deg = (partial[0] + partial[1]) + (partial[2] + partial[3]) + 1.0f;
    dinv[row] = 1.0f / sqrtf(deg + 1e-8f);
  }
}

// ---- kernel 2: yT[f][i] = dinv[i] * x[i][f]  (bf16, transposed for NT GEMM) ----
__global__ __launch_bounds__(256) void k_scale_t(const float* __restrict__ x,
                                                 const float* __restrict__ dinv,
                                                 short* __restrict__ yT) {
  __shared__ float tile[64][129];
  const int r0 = blockIdx.x * 64;
  const int tid = threadIdx.x;
#pragma unroll
  for (int it = 0; it < 8; ++it) {
    int q = it * 256 + tid;
    int r = q >> 5;
    int c = q & 31;
    float4 v = ((const float4*)(x + (size_t)(r0 + r) * FF))[c];
    float d = dinv[r0 + r];
    tile[r][c * 4 + 0] = v.x * d;
    tile[r][c * 4 + 1] = v.y * d;
    tile[r][c * 4 + 2] = v.z * d;
    tile[r][c * 4 + 3] = v.w * d;
  }
  __syncthreads();
  const int f = tid >> 1;
  const int i0 = (tid & 1) * 32;
#pragma unroll
  for (int g = 0; g < 4; ++g) {
    bf16x8 o;
#pragma unroll
    for (int j = 0; j < 8; ++j) o[j] = f2bf(tile[i0 + g * 8 + j][f]);
    *(bf16x8*)(yT + (size_t)f * NN + r0 + i0 + g * 8) = o;
  }
}

// ---- kernel 3: zpart[ks] = adj[:, ksliced] @ y. K-split MFMA GEMM. ----
// 1024 blocks (128 M-tiles x 8 K-slices), 512 thr = 8 waves (2M x 4N),
// BM=64, BN=128(all), BK=32. Dbuf LDS (30.7 KB) + raw barrier + 2-phase
// register prefetch — the proven R7 schedule at HALF the footprint:
// launch_bounds(512,6) targets VGPR<=85 -> 3 blocks/CU (24 waves), i.e.
// 3 independent load-issuing gangs per CU instead of 2 (issue smoothing).
// MFMA order identical to the BK=64 version -> bit-identical output.
__global__ __launch_bounds__(512, 6) void k_gemm(const float* __restrict__ adj,
                                                 const short* __restrict__ yT,
                                                 short* __restrict__ zpart) {
  __shared__ short As[2][BM][40];     // bf16, +8 pad
  __shared__ short Bs[2][128][40];
  const int tid = threadIdx.x;
  const int wave = tid >> 6;
  const int lane = tid & 63;
  const int mb = 127 - (int)(blockIdx.x & 127);   // reverse: read L3-warm rows first
  const int ks = blockIdx.x >> 7;
  const int row0 = mb * BM;
  const size_t kbase = (size_t)ks * KCH;

  // staging maps: A = 64 rows x 32 f32 (1 float4/thread);
  //               B = 128 rows x 32 bf16 (1 bf16x8/thread)
  const int s_ar = tid >> 3;          // 8 threads/row x 4 f32
  const int s_ac = (tid & 7) * 4;
  const int s_br = tid >> 2;          // 4 threads/row x 8 bf16
  const int s_bc = (tid & 3) * 8;
  const float* pa = adj + (size_t)(row0 + s_ar) * NN + kbase + s_ac;
  const short* pb = yT + (size_t)s_br * NN + kbase + s_bc;

  const int wm = (wave >> 2) * 32;   // 0/32
  const int wn = (wave & 3) * 32;    // 0/32/64/96
  const int fr = lane & 15;
  const int kh = (lane >> 4) * 8;

  f32x4 acc00 = {0.f,0.f,0.f,0.f}, acc01 = acc00, acc10 = acc00, acc11 = acc00;

  float4 aX, aY;
  bf16x8 bX, bY;

#define LOADT(av, bv, koff) do {                                               \
    av = *(const float4*)(pa + (koff));                                        \
    bv = *(const bf16x8*)(pb + (koff));                                        \
  } while (0)

#define STAGE(BUF, av, bv) do {                                                \
    s16x4 ap_;                                                                 \
    ap_.x = f2bf(av.x); ap_.y = f2bf(av.y);                                    \
    ap_.z = f2bf(av.z); ap_.w = f2bf(av.w);                                    \
    *(s16x4*)&As[BUF][s_ar][s_ac] = ap_;                                       \
    *(bf16x8*)&Bs[BUF][s_br][s_bc] = bv;                                       \
  } while (0)

#define COMPUTE(BUF) do {                                                      \
    bf16x8 a0 = *(const bf16x8*)&As[BUF][wm + fr][kh];                         \
    bf16x8 a1 = *(const bf16x8*)&As[BUF][wm + 16 + fr][kh];                    \
    bf16x8 b0 = *(const bf16x8*)&Bs[BUF][wn + fr][kh];                         \
    bf16x8 b1 = *(const bf16x8*)&Bs[BUF][wn + 16 + fr][kh];                    \
    acc00 = __builtin_amdgcn_mfma_f32_16x16x32_bf16(a0, b0, acc00, 0, 0, 0);   \
    acc01 = __builtin_amdgcn_mfma_f32_16x16x32_bf16(a0, b1, acc01, 0, 0, 0);   \
    acc10 = __builtin_amdgcn_mfma_f32_16x16x32_bf16(a1, b0, acc10, 0, 0, 0);   \
    acc11 = __builtin_amdgcn_mfma_f32_16x16x32_bf16(a1, b1, acc11, 0, 0, 0);   \
  } while (0)

  // prologue: tile0 -> X -> LDS0; tile1 -> Y (stays in flight)
  LOADT(aX, bX, 0);
  LOADT(aY, bY, BK);
  STAGE(0, aX, bX);    // counted vmcnt: waits only X's loads
  BAR();

  for (int step = 0; step < NSTEP; step += 2) {
    // phase A: compute LDS0 (tile step); issue tile step+2 -> X; stage Y -> LDS1
    if (step + 2 < NSTEP) LOADT(aX, bX, (step + 2) * BK);
    COMPUTE(0);
    STAGE(1, aY, bY);
    BAR();
    // phase B: compute LDS1 (tile step+1); issue tile step+3 -> Y; stage X -> LDS0
    if (step + 3 < NSTEP) LOADT(aY, bY, (step + 3) * BK);
    COMPUTE(1);
    if (step + 2 < NSTEP) STAGE(0, aX, bX);
    BAR();
  }

  // epilogue: D layout col=lane&15, row=(lane>>4)*4+r ; store bf16 partials
  const int r4 = (lane >> 4) * 4;
  short* zp = zpart + ((size_t)ks << 20);   // slice stride 8192*128
#pragma unroll
  for (int r = 0; r < 4; ++r) {
    int gi0 = row0 + wm + r4 + r;
    int gi1 = gi0 + 16;
    zp[(size_t)gi0 * FF + wn + fr]      = f2bf(acc00[r]);
    zp[(size_t)gi0 * FF + wn + 16 + fr] = f2bf(acc01[r]);
    zp[(size_t)gi1 * FF + wn + fr]      = f2bf(acc10[r]);
    zp[(size_t)gi1 * FF + wn + 16 + fr] = f2bf(acc11[r]);
  }
#undef LOADT
#undef STAGE
#undef COMPUTE
}

// ---- kernel 4: out = relu((dinv*(sum_ks zpart + dinv*x)) @ W) ----
__global__ __launch_bounds__(256) void k_out(const short* __restrict__ zpart,
                                             const float* __restrict__ x,
                                             const float* __restrict__ dinv,
                                             const float* __restrict__ w,
                                             float* __restrict__ out) {
  __shared__ float zs[16][128];
  const int r0 = blockIdx.x * 16;
  const int tid = threadIdx.x;
#pragma unroll
  for (int half = 0; half < 2; ++half) {
    int p = half * 256 + tid;
    int r = p >> 5;
    int c4 = p & 31;
    int gi = r0 + r;
    const short* base = zpart + (size_t)gi * FF + c4 * 4;
    float s0 = 0.f, s1 = 0.f, s2 = 0.f, s3 = 0.f;
#pragma unroll
    for (int sidx = 0; sidx < KS; ++sidx) {
      short4 v = *(const short4*)(base + ((size_t)sidx << 20));
      s0 += bf2f(v.x); s1 += bf2f(v.y); s2 += bf2f(v.z); s3 += bf2f(v.w);
    }
    float4 xv = *(const float4*)(x + (size_t)gi * FF + c4 * 4);
    float di = dinv[gi];
    float di2 = di * di;
    zs[r][c4 * 4 + 0] = di * s0 + di2 * xv.x;
    zs[r][c4 * 4 + 1] = di * s1 + di2 * xv.y;
    zs[r][c4 * 4 + 2] = di * s2 + di2 * xv.z;
    zs[r][c4 * 4 + 3] = di * s3 + di2 * xv.w;
  }
  __syncthreads();
  const int f = tid & 127;
  const int rg = (tid >> 7) * 8;
  float acc[8] = {0.f, 0.f, 0.f, 0.f, 0.f, 0.f, 0.f, 0.f};
#pragma unroll 4
  for (int k = 0; k < 128; ++k) {
    float wv = w[k * FF + f];
#pragma unroll
    for (int r = 0; r < 8; ++r) acc[r] += zs[rg + r][k] * wv;
  }
#pragma unroll
  for (int r = 0; r < 8; ++r) {
    out[(size_t)(r0 + rg + r) * FF + f] = fmaxf(acc[r], 0.0f);
  }
}

extern "C" void kernel_launch(void* const* d_in, const int* in_sizes, int n_in,
                              void* d_out, int out_size, void* d_ws, size_t ws_size,
                              hipStream_t stream) {
  const float* x   = (const float*)d_in[0];
  const float* adj = (const float*)d_in[1];
  const float* w   = (const float*)d_in[2];
  float* out = (float*)d_out;

  float* dinv  = (float*)d_ws;                                  // 32 KiB @ 0
  short* yT    = (short*)((char*)d_ws + 64 * 1024);             // 2 MiB bf16 [128][8192]
  short* zpart = (short*)((char*)d_ws + 4 * 1024 * 1024);       // 16 MiB bf16 [8][8192][128]

  k_deg    <<<NN,       256, 0, stream>>>(adj, dinv);
  k_scale_t<<<NN / 64,  256, 0, stream>>>(x, dinv, yT);
  k_gemm   <<<128 * KS, 512, 0, stream>>>(adj, yT, zpart);
  k_out    <<<NN / 16,  256, 0, stream>>>(zpart, x, dinv, w, out);
}

// Round 12
// 112.854 us; speedup vs baseline: 4.2053x; 1.0654x over previous
//
#include <hip/hip_runtime.h>
#include <hip/hip_bf16.h>

#define NN 8192
#define FF 128
#define BM 64
#define BK 64
#define KS 8
#define KCH (NN / KS)      // 1024 K per block
#define NSTEP (KCH / BK)   // 16

typedef __attribute__((ext_vector_type(8))) short bf16x8;   // 8 bf16 (4 VGPR)
typedef __attribute__((ext_vector_type(4))) float f32x4;

__device__ __forceinline__ short f2bf(float f) {
  unsigned u = __float_as_uint(f);
  u += 0x7FFFu + ((u >> 16) & 1u);
  return (short)(u >> 16);
}
__device__ __forceinline__ float bf2f(short s) {
  return __uint_as_float(((unsigned)(unsigned short)s) << 16);
}

// async global->LDS DMA, 16B per lane. Dest = wave-uniform LDS base + lane*16.
// Consumes NO VGPRs -> the compiler cannot sink it for register pressure
// (R9/R10 post-mortem: reg-staged prefetch always got sunk to its consumer).
__device__ __forceinline__ void dma16(const void* g, void* lds) {
  __builtin_amdgcn_global_load_lds(
      (const __attribute__((address_space(1))) unsigned int*)(uintptr_t)g,
      (__attribute__((address_space(3))) unsigned int*)(lds),
      16, 0, 0);
}

// packed f32x2 -> bf16x2 (RNE, same results as f2bf), 4 inst per 8 floats
__device__ __forceinline__ bf16x8 cvt8(float4 lo, float4 hi) {
  union { bf16x8 v; unsigned u[4]; } r;
  asm("v_cvt_pk_bf16_f32 %0, %1, %2" : "=v"(r.u[0]) : "v"(lo.x), "v"(lo.y));
  asm("v_cvt_pk_bf16_f32 %0, %1, %2" : "=v"(r.u[1]) : "v"(lo.z), "v"(lo.w));
  asm("v_cvt_pk_bf16_f32 %0, %1, %2" : "=v"(r.u[2]) : "v"(hi.x), "v"(hi.y));
  asm("v_cvt_pk_bf16_f32 %0, %1, %2" : "=v"(r.u[3]) : "v"(hi.z), "v"(hi.w));
  return r.v;
}

// ---- kernel 1: deg[i] = rowsum(adj)+1 ; dinv[i] = (deg+1e-8)^-0.5 ----
__global__ __launch_bounds__(256) void k_deg(const float* __restrict__ adj,
                                             float* __restrict__ dinv) {
  const int row = blockIdx.x;
  const float4* p = (const float4*)(adj + (size_t)row * NN);
  float s = 0.f;
#pragma unroll
  for (int it = 0; it < 8; ++it) {
    float4 v = p[it * 256 + threadIdx.x];
    s += (v.x + v.y) + (v.z + v.w);
  }
#pragma unroll
  for (int off = 32; off > 0; off >>= 1) s += __shfl_down(s, off, 64);
  __shared__ float partial[4];
  if ((threadIdx.x & 63) == 0) partial[threadIdx.x >> 6] = s;
  __syncthreads();
  if (threadIdx.x == 0) {
    float deg = (partial[0] + partial[1]) + (partial[2] + partial[3]) + 1.0f;
    dinv[row] = 1.0f / sqrtf(deg + 1e-8f);
  }
}

// ---- kernel 2: yT[f][i] = dinv[i] * x[i][f]  (bf16, transposed for NT GEMM) ----
__global__ __launch_bounds__(256) void k_scale_t(const float* __restrict__ x,
                                                 const float* __restrict__ dinv,
                                                 short* __restrict__ yT) {
  __shared__ float tile[64][129];
  const int r0 = blockIdx.x * 64;
  const int tid = threadIdx.x;
#pragma unroll
  for (int it = 0; it < 8; ++it) {
    int q = it * 256 + tid;
    int r = q >> 5;
    int c = q & 31;
    float4 v = ((const float4*)(x + (size_t)(r0 + r) * FF))[c];
    float d = dinv[r0 + r];
    tile[r][c * 4 + 0] = v.x * d;
    tile[r][c * 4 + 1] = v.y * d;
    tile[r][c * 4 + 2] = v.z * d;
    tile[r][c * 4 + 3] = v.w * d;
  }
  __syncthreads();
  const int f = tid >> 1;
  const int i0 = (tid & 1) * 32;
#pragma unroll
  for (int g = 0; g < 4; ++g) {
    bf16x8 o;
#pragma unroll
    for (int j = 0; j < 8; ++j) o[j] = f2bf(tile[i0 + g * 8 + j][f]);
    *(bf16x8*)(yT + (size_t)f * NN + r0 + i0 + g * 8) = o;
  }
}

// ---- kernel 3: zpart[ks] = adj[:, ksliced] @ y. gload_lds MFMA GEMM. ----
// 1024 blocks (128 M-tiles x 8 K-slices), 512 thr = 8 waves (2M x 4N),
// BM=64, BN=128(all), BK=64. Staging is pure DMA (global_load_lds x4/wave,
// zero VGPRs, zero staging VALU); A kept f32 in LDS, converted to bf16 at
// consume time (v_cvt_pk_bf16_f32). LDS linear (DMA requires it) with
// rule-#21 XOR swizzle: inverse-swizzled GLOBAL source + swizzled READ,
// 16B chunks, chunk ^= (row&7) -> 8-cyc (minimal) ds_read_b128. One barrier
// per phase; DMA issued at phase start has the whole COMPUTE to land, so the
// vmcnt(0) drain in __syncthreads is ~free. LDS 64 KB -> 2 blocks/CU.
__global__ __launch_bounds__(512) void k_gemm(const float* __restrict__ adj,
                                              const short* __restrict__ yT,
                                              short* __restrict__ zpart) {
  __shared__ float Asf[2][BM * BK];        // 2 x 16 KB, f32, swizzled chunks
  __shared__ short Bsf[2][128 * BK];       // 2 x 16 KB, bf16, swizzled chunks
  const int tid = threadIdx.x;
  const int wave = tid >> 6;
  const int lane = tid & 63;
  const int mb = 127 - (int)(blockIdx.x & 127);   // reverse: read L3-warm rows first
  const int ks = blockIdx.x >> 7;
  const int row0 = mb * BM;
  const size_t kbase = (size_t)ks * KCH;

  // --- DMA source map (inverse-swizzled so linear LDS dest ends up swizzled).
  // A: chunk n (of 1024) = 16B = 4 f32. n = (w + i*8)*64 + lane; i=0 -> n=tid.
  //    row = n>>4 (i=1: +32, same row&7), physChunkInRow = n&15,
  //    logical chunk = phys ^ (row&7).
  const int rowA = tid >> 4;                       // 0..31
  const int c4l  = (tid & 15) ^ (rowA & 7);
  const float* pa0 = adj + (size_t)(row0 + rowA) * NN + kbase + c4l * 4;
  const float* pa1 = pa0 + (size_t)32 * NN;        // i=1: rows +32
  // B: chunk n = 16B = 8 bf16. row = n>>3 (i=1: +64), logical = (n&7)^(row&7).
  const int rowB = tid >> 3;                       // 0..63
  const int c8l  = (tid & 7) ^ (rowB & 7);
  const short* pb0 = yT + (size_t)rowB * NN + kbase + c8l * 8;
  const short* pb1 = pb0 + (size_t)64 * NN;        // i=1: rows +64

  const int ldsOff = wave * 1024;                  // wave's chunk window (bytes)

#define STAGE_DMA(BUF, koff) do {                                              \
    char* la = (char*)&Asf[BUF][0] + ldsOff;                                   \
    char* lb = (char*)&Bsf[BUF][0] + ldsOff;                                   \
    dma16(pa0 + (koff), la);                                                   \
    dma16(pa1 + (koff), la + 8192);                                            \
    dma16(pb0 + (koff), lb);                                                   \
    dma16(pb1 + (koff), lb + 8192);                                            \
  } while (0)

  // --- compute-side fragment map (proven MFMA layout, swizzled addresses)
  const int wm = (wave >> 2) * 32;   // 0/32
  const int wn = (wave & 3) * 32;    // 0/32/64/96
  const int fr = lane & 15;
  const int kh = (lane >> 4) * 8;    // 0/8/16/24 -> but only 0/8 per kk-half
  const int khq = kh >> 2;           // A chunk sub-offset (f32 16B chunks)
  const int kh8 = kh >> 3;           // B chunk sub-offset
  const int sw  = fr & 7;            // row swizzle (wm/wn/16 are 0 mod 8)
  const int ra0 = wm + fr, ra1 = ra0 + 16;
  const int rb0 = wn + fr, rb1 = rb0 + 16;

  f32x4 acc00 = {0.f,0.f,0.f,0.f}, acc01 = acc00, acc10 = acc00, acc11 = acc00;

#define COMPUTE(BUF) do {                                                      \
    const char* Ab = (const char*)&Asf[BUF][0];                                \
    const char* Bb = (const char*)&Bsf[BUF][0];                                \
    _Pragma("unroll")                                                          \
    for (int kk = 0; kk < 2; ++kk) {                                           \
      int c4 = kk * 8 + khq;                                                   \
      int c8 = kk * 4 + kh8;                                                   \
      float4 lo0 = *(const float4*)(Ab + ra0 * 256 + (((c4    ) ^ sw) << 4));  \
      float4 hi0 = *(const float4*)(Ab + ra0 * 256 + (((c4 + 1) ^ sw) << 4));  \
      float4 lo1 = *(const float4*)(Ab + ra1 * 256 + (((c4    ) ^ sw) << 4));  \
      float4 hi1 = *(const float4*)(Ab + ra1 * 256 + (((c4 + 1) ^ sw) << 4));  \
      bf16x8 b0 = *(const bf16x8*)(Bb + rb0 * 128 + ((c8 ^ sw) << 4));         \
      bf16x8 b1 = *(const bf16x8*)(Bb + rb1 * 128 + ((c8 ^ sw) << 4));         \
      bf16x8 a0 = cvt8(lo0, hi0);                                              \
      bf16x8 a1 = cvt8(lo1, hi1);                                              \
      acc00 = __builtin_amdgcn_mfma_f32_16x16x32_bf16(a0, b0, acc00, 0, 0, 0); \
      acc01 = __builtin_amdgcn_mfma_f32_16x16x32_bf16(a0, b1, acc01, 0, 0, 0); \
      acc10 = __builtin_amdgcn_mfma_f32_16x16x32_bf16(a1, b0, acc10, 0, 0, 0); \
      acc11 = __builtin_amdgcn_mfma_f32_16x16x32_bf16(a1, b1, acc11, 0, 0, 0); \
    }                                                                          \
  } while (0)

  // prologue: DMA tile 0 -> buf0; drain; then steady 2-phase
  STAGE_DMA(0, 0);
  __syncthreads();

  int buf = 0;
  for (int t = 0; t < NSTEP; ++t) {
    if (t + 1 < NSTEP) STAGE_DMA(buf ^ 1, (t + 1) * BK);
    __builtin_amdgcn_sched_barrier(0);   // pin: DMA issues before compute
    COMPUTE(buf);
    __syncthreads();                     // readers of buf done + DMA landed
    buf ^= 1;
  }

  // epilogue: D layout col=lane&15, row=(lane>>4)*4+r ; store bf16 partials
  const int r4 = (lane >> 4) * 4;
  short* zp = zpart + ((size_t)ks << 20);   // slice stride 8192*128
#pragma unroll
  for (int r = 0; r < 4; ++r) {
    int gi0 = row0 + wm + r4 + r;
    int gi1 = gi0 + 16;
    zp[(size_t)gi0 * FF + wn + fr]      = f2bf(acc00[r]);
    zp[(size_t)gi0 * FF + wn + 16 + fr] = f2bf(acc01[r]);
    zp[(size_t)gi1 * FF + wn + fr]      = f2bf(acc10[r]);
    zp[(size_t)gi1 * FF + wn + 16 + fr] = f2bf(acc11[r]);
  }
#undef STAGE_DMA
#undef COMPUTE
}

// ---- kernel 4: out = relu((dinv*(sum_ks zpart + dinv*x)) @ W) ----
__global__ __launch_bounds__(256) void k_out(const short* __restrict__ zpart,
                                             const float* __restrict__ x,
                                             const float* __restrict__ dinv,
                                             const float* __restrict__ w,
                                             float* __restrict__ out) {
  __shared__ float zs[16][128];
  const int r0 = blockIdx.x * 16;
  const int tid = threadIdx.x;
#pragma unroll
  for (int half = 0; half < 2; ++half) {
    int p = half * 256 + tid;
    int r = p >> 5;
    int c4 = p & 31;
    int gi = r0 + r;
    const short* base = zpart + (size_t)gi * FF + c4 * 4;
    float s0 = 0.f, s1 = 0.f, s2 = 0.f, s3 = 0.f;
#pragma unroll
    for (int sidx = 0; sidx < KS; ++sidx) {
      short4 v = *(const short4*)(base + ((size_t)sidx << 20));
      s0 += bf2f(v.x); s1 += bf2f(v.y); s2 += bf2f(v.z); s3 += bf2f(v.w);
    }
    float4 xv = *(const float4*)(x + (size_t)gi * FF + c4 * 4);
    float di = dinv[gi];
    float di2 = di * di;
    zs[r][c4 * 4 + 0] = di * s0 + di2 * xv.x;
    zs[r][c4 * 4 + 1] = di * s1 + di2 * xv.y;
    zs[r][c4 * 4 + 2] = di * s2 + di2 * xv.z;
    zs[r][c4 * 4 + 3] = di * s3 + di2 * xv.w;
  }
  __syncthreads();
  const int f = tid & 127;
  const int rg = (tid >> 7) * 8;
  float acc[8] = {0.f, 0.f, 0.f, 0.f, 0.f, 0.f, 0.f, 0.f};
#pragma unroll 4
  for (int k = 0; k < 128; ++k) {
    float wv = w[k * FF + f];
#pragma unroll
    for (int r = 0; r < 8; ++r) acc[r] += zs[rg + r][k] * wv;
  }
#pragma unroll
  for (int r = 0; r < 8; ++r) {
    out[(size_t)(r0 + rg + r) * FF + f] = fmaxf(acc[r], 0.0f);
  }
}

extern "C" void kernel_launch(void* const* d_in, const int* in_sizes, int n_in,
                              void* d_out, int out_size, void* d_ws, size_t ws_size,
                              hipStream_t stream) {
  const float* x   = (const float*)d_in[0];
  const float* adj = (const float*)d_in[1];
  const float* w   = (const float*)d_in[2];
  float* out = (float*)d_out;

  float* dinv  = (float*)d_ws;                                  // 32 KiB @ 0
  short* yT    = (short*)((char*)d_ws + 64 * 1024);             // 2 MiB bf16 [128][8192]
  short* zpart = (short*)((char*)d_ws + 4 * 1024 * 1024);       // 16 MiB bf16 [8][8192][128]

  k_deg    <<<NN,       256, 0, stream>>>(adj, dinv);
  k_scale_t<<<NN / 64,  256, 0, stream>>>(x, dinv, yT);
  k_gemm   <<<128 * KS, 512, 0, stream>>>(adj, yT, zpart);
  k_out    <<<NN / 16,  256, 0, stream>>>(zpart, x, dinv, w, out);
}